// Round 1
// baseline (123.500 us; speedup 1.0000x reference)
//
#include <hip/hip_runtime.h>

typedef unsigned short ushort_t;
typedef __attribute__((ext_vector_type(8))) short bfrag;
typedef __attribute__((ext_vector_type(4))) float f4;

// ---------- constants (problem instance is fixed) ----------
// B=4, D=256, H=W=64, num_levels=4, radius=4
#define NB 4
#define ND 256
#define NH 64
#define NW 64
#define NQ (NH * NW)            // 4096 queries per batch
#define MTOT 5440               // 4096 + 1024 + 256 + 64
#define MPAD 5504               // 43 * 128
#define NLVL 4
#define NCH (NLVL * 81)         // 324 output channels

__device__ __forceinline__ float bf2f(ushort_t u) {
    return __uint_as_float(((unsigned)u) << 16);
}
__device__ __forceinline__ ushort_t f2bf(float f) {
    unsigned u = __float_as_uint(f);
    unsigned r = (u + 0x7fffu + ((u >> 16) & 1u)) >> 16;
    return (ushort_t)r;
}

__device__ __forceinline__ void gload_lds16(const void* g, void* l) {
    __builtin_amdgcn_global_load_lds(
        (const __attribute__((address_space(1))) unsigned int*)g,
        (__attribute__((address_space(3))) unsigned int*)l, 16, 0, 0);
}

// ---------- kernel 1: transpose [b][256][4096] f32 -> [b][4096][256] bf16 ----------
__global__ __launch_bounds__(256) void transpose_cvt(
    const float* __restrict__ in, ushort_t* __restrict__ outp,
    size_t in_bstride, size_t out_bstride)
{
    __shared__ float tile[64][65];
    const int tid = threadIdx.x;
    const int n0 = blockIdx.x * 64, d0 = blockIdx.y * 64, b = blockIdx.z;
    const float* ib = in + (size_t)b * in_bstride;
    ushort_t* ob = outp + (size_t)b * out_bstride;
    const int nl = tid & 63, dg = tid >> 6;
#pragma unroll
    for (int i = 0; i < 16; i++) {
        int dl = dg + i * 4;
        tile[dl][nl] = ib[(size_t)(d0 + dl) * NQ + n0 + nl];
    }
    __syncthreads();
    const int dl = tid & 63, ng = tid >> 6;
#pragma unroll
    for (int i = 0; i < 16; i++) {
        int nn = ng + i * 4;
        ob[(size_t)(n0 + nn) * ND + d0 + dl] = f2bf(tile[dl][nn]);
    }
}

// ---------- kernel 2: avg-pool 2x2 in [m][d] bf16 layout (within B_all slab) ----------
__global__ void pool_kernel(ushort_t* __restrict__ Ball, int Wlo, int in_off, int out_off)
{
    int t = blockIdx.x * 256 + threadIdx.x;
    int d = t & 255;
    int rest = t >> 8;
    int Nl = Wlo * Wlo;
    int m = rest % Nl;
    int b = rest / Nl;
    if (b >= NB) return;
    int y = m / Wlo, x = m - y * Wlo;
    int Wi = Wlo * 2;
    const ushort_t* src = Ball + (size_t)b * MPAD * ND;
    float s = 0.f;
#pragma unroll
    for (int iy = 0; iy < 2; iy++)
#pragma unroll
        for (int ix = 0; ix < 2; ix++)
            s += bf2f(src[(size_t)(in_off + (2 * y + iy) * Wi + (2 * x + ix)) * ND + d]);
    Ball[(size_t)b * MPAD * ND + (size_t)(out_off + m) * ND + d] = f2bf(s * 0.25f);
}

// ---------- kernel 3: bf16 MFMA GEMM  C[n][m] = (1/16) sum_d A[n][d] * Bm[m][d] ----------
__global__ __launch_bounds__(256) void gemm_corr(
    const ushort_t* __restrict__ A,    // [NB][4096][256] bf16
    const ushort_t* __restrict__ Bm,   // [NB][MPAD][256] bf16
    ushort_t* __restrict__ C,          // [z][4096][MPAD] bf16
    int b0, long long c_bstride)
{
    __shared__ ushort_t As[128 * 32];
    __shared__ ushort_t Bs[128 * 32];
    const int tid = threadIdx.x;
    const int lane = tid & 63;
    const int wv = tid >> 6;
    const int wr = wv >> 1, wc = wv & 1;
    const int bx = blockIdx.x;   // m tile (43)
    const int by = blockIdx.y;   // n tile (32)
    const int b = b0 + blockIdx.z;
    const ushort_t* Ab = A + (size_t)b * NQ * ND + (size_t)by * 128 * ND;
    const ushort_t* Bb = Bm + (size_t)b * MPAD * ND + (size_t)bx * 128 * ND;
    ushort_t* Cb = C + (size_t)blockIdx.z * (size_t)c_bstride;

    f4 acc[4][4] = {};

    const int r0 = tid >> 2;   // 0..63
    const int c8 = tid & 3;    // which 8-elem chunk in the 32-wide K slice

    for (int kk = 0; kk < ND; kk += 32) {
        __syncthreads();
        gload_lds16(Ab + (size_t)r0 * ND + kk + c8 * 8,        &As[(size_t)tid * 8]);
        gload_lds16(Ab + (size_t)(64 + r0) * ND + kk + c8 * 8, &As[(size_t)(256 + tid) * 8]);
        gload_lds16(Bb + (size_t)r0 * ND + kk + c8 * 8,        &Bs[(size_t)tid * 8]);
        gload_lds16(Bb + (size_t)(64 + r0) * ND + kk + c8 * 8, &Bs[(size_t)(256 + tid) * 8]);
        __syncthreads();
        bfrag a[4], bb[4];
#pragma unroll
        for (int mi = 0; mi < 4; mi++)
            a[mi] = *reinterpret_cast<const bfrag*>(
                &As[(wr * 64 + mi * 16 + (lane & 15)) * 32 + (lane >> 4) * 8]);
#pragma unroll
        for (int ni = 0; ni < 4; ni++)
            bb[ni] = *reinterpret_cast<const bfrag*>(
                &Bs[(wc * 64 + ni * 16 + (lane & 15)) * 32 + (lane >> 4) * 8]);
#pragma unroll
        for (int mi = 0; mi < 4; mi++)
#pragma unroll
            for (int ni = 0; ni < 4; ni++)
                acc[mi][ni] = __builtin_amdgcn_mfma_f32_16x16x32_bf16(
                    a[mi], bb[ni], acc[mi][ni], 0, 0, 0);
    }

    const int row_base = by * 128 + wr * 64 + ((lane >> 4) << 2);
    const int col_base = bx * 128 + wc * 64 + (lane & 15);
#pragma unroll
    for (int mi = 0; mi < 4; mi++)
#pragma unroll
        for (int ni = 0; ni < 4; ni++)
#pragma unroll
            for (int j = 0; j < 4; j++) {
                int row = row_base + mi * 16 + j;
                int col = col_base + ni * 16;
                Cb[(size_t)row * MPAD + col] = f2bf(acc[mi][ni][j] * 0.0625f);
            }
}

// ---------- kernel 4: bilinear sampling ----------
// block = 256 threads handles 16 queries x 1 level; grid (256 qgroups, 4 levels, z batches)
__global__ __launch_bounds__(256) void sample_kernel(
    const ushort_t* __restrict__ corr,   // [z][4096][MPAD] bf16
    const float* __restrict__ coords,    // [NB][2][64][64] f32
    float* __restrict__ out,             // [NB][324][64][64] f32
    int b0, long long c_bstride)
{
    __shared__ int   X0s[16], Y0s[16];
    __shared__ float wxs[16], wys[16];
    __shared__ float Dl[16 * 101];
    const int tid = threadIdx.x;
    const int g   = blockIdx.x;          // query group (16 queries)
    const int lvl = blockIdx.y;
    const int b   = b0 + blockIdx.z;
    const ushort_t* cb = corr + (size_t)blockIdx.z * (size_t)c_bstride;
    const int Wl = NW >> lvl;
    const int lvloff = (lvl == 0) ? 0 : (lvl == 1) ? 4096 : (lvl == 2) ? 5120 : 5376;

    if (tid < 16) {
        int q = g * 16 + tid;
        float cx = coords[(size_t)(b * 2 + 0) * NQ + q];
        float cy = coords[(size_t)(b * 2 + 1) * NQ + q];
        float s = 1.0f / (float)(1 << lvl);
        float xl = cx * s, yl = cy * s;
        float fx = floorf(xl), fy = floorf(yl);
        X0s[tid] = (int)fx;
        Y0s[tid] = (int)fy;
        wxs[tid] = xl - fx;
        wys[tid] = yl - fy;
    }
    __syncthreads();

    // gather the 10x10 window of corr values per query into LDS
#pragma unroll
    for (int r = 0; r < 7; r++) {
        int e = r * 256 + tid;
        if (e < 16 * 100) {
            int qi = e / 100;
            int el = e - qi * 100;
            int v = el / 10;          // y offset index
            int u = el - v * 10;      // x offset index
            int xx = X0s[qi] - 4 + u;
            int yy = Y0s[qi] - 4 + v;
            float val = 0.f;
            if ((unsigned)xx < (unsigned)Wl && (unsigned)yy < (unsigned)Wl) {
                ushort_t raw = cb[(size_t)(g * 16 + qi) * MPAD + lvloff + yy * Wl + xx];
                val = bf2f(raw);
            }
            Dl[qi * 101 + el] = val;
        }
    }
    __syncthreads();

    // 81 bilinear outputs per query, lane<->query for coalesced writes
#pragma unroll
    for (int r = 0; r < 6; r++) {
        int e = r * 256 + tid;
        if (e < 16 * 81) {
            int qi = e & 15;
            int c = e >> 4;           // 0..80 = i*9 + j
            int i = c / 9;            // x-offset grid index
            int j = c - i * 9;        // y-offset grid index
            float wx = wxs[qi], wy = wys[qi];
            const float* dq = &Dl[qi * 101];
            float d00 = dq[j * 10 + i];
            float d10 = dq[j * 10 + i + 1];
            float d01 = dq[(j + 1) * 10 + i];
            float d11 = dq[(j + 1) * 10 + i + 1];
            float vx0 = d00 + wx * (d10 - d00);
            float vx1 = d01 + wx * (d11 - d01);
            float val = vx0 + wy * (vx1 - vx0);
            out[((size_t)b * NCH + lvl * 81 + c) * NQ + g * 16 + qi] = val;
        }
    }
}

extern "C" void kernel_launch(void* const* d_in, const int* in_sizes, int n_in,
                              void* d_out, int out_size, void* d_ws, size_t ws_size,
                              hipStream_t stream)
{
    const float* fmap1  = (const float*)d_in[0];
    const float* fmap2  = (const float*)d_in[1];
    const float* coords = (const float*)d_in[2];
    float* out = (float*)d_out;

    char* ws = (char*)d_ws;
    const size_t A_BYTES = (size_t)NB * NQ * ND * 2;       // 8,388,608
    const size_t B_BYTES = (size_t)NB * MPAD * ND * 2;     // 11,272,192
    ushort_t* Abf  = (ushort_t*)ws;
    ushort_t* Ball = (ushort_t*)(ws + A_BYTES);
    ushort_t* corr = (ushort_t*)(ws + A_BYTES + B_BYTES);
    const size_t CORR_FULL = (size_t)NB * NQ * MPAD * 2;   // ~180.4 MB
    const bool full = (ws_size >= A_BYTES + B_BYTES + CORR_FULL);

    // transpose+convert both feature maps
    transpose_cvt<<<dim3(64, 4, NB), 256, 0, stream>>>(fmap1, Abf,  (size_t)ND * NQ, (size_t)NQ * ND);
    transpose_cvt<<<dim3(64, 4, NB), 256, 0, stream>>>(fmap2, Ball, (size_t)ND * NQ, (size_t)MPAD * ND);

    // pyramid pooling of f2 features (levels 1..3)
    pool_kernel<<<(NB * 1024 * ND) / 256, 256, 0, stream>>>(Ball, 32, 0,    4096);
    pool_kernel<<<(NB * 256  * ND) / 256, 256, 0, stream>>>(Ball, 16, 4096, 5120);
    pool_kernel<<<(NB * 64   * ND) / 256, 256, 0, stream>>>(Ball, 8,  5120, 5376);

    if (full) {
        gemm_corr<<<dim3(43, 32, NB), 256, 0, stream>>>(Abf, Ball, corr, 0, (long long)NQ * MPAD);
        sample_kernel<<<dim3(256, NLVL, NB), 256, 0, stream>>>(corr, coords, out, 0, (long long)NQ * MPAD);
    } else {
        for (int b = 0; b < NB; b++) {
            gemm_corr<<<dim3(43, 32, 1), 256, 0, stream>>>(Abf, Ball, corr, b, 0);
            sample_kernel<<<dim3(256, NLVL, 1), 256, 0, stream>>>(corr, coords, out, b, 0);
        }
    }
}

// Round 2
// 112.643 us; speedup vs baseline: 1.0964x; 1.0964x over previous
//
#include <hip/hip_runtime.h>

typedef unsigned short ushort_t;
typedef __attribute__((ext_vector_type(8))) short bfrag;
typedef __attribute__((ext_vector_type(4))) float f4;

// B=4, D=256, H=W=64, num_levels=4, radius=4
#define NB 4
#define ND 256
#define NH 64
#define NW 64
#define NQ (NH * NW)            // 4096 queries per batch
#define MPAD 5504               // 43 * 128 rows of pooled-f2 features
#define NLVL 4
#define NCH (NLVL * 81)

__device__ __forceinline__ float bf2f(ushort_t u) {
    return __uint_as_float(((unsigned)u) << 16);
}
__device__ __forceinline__ ushort_t f2bf(float f) {
    unsigned u = __float_as_uint(f);
    unsigned r = (u + 0x7fffu + ((u >> 16) & 1u)) >> 16;
    return (ushort_t)r;
}

__device__ __forceinline__ void gload_lds16(const void* g, void* l) {
    __builtin_amdgcn_global_load_lds(
        (const __attribute__((address_space(1))) unsigned int*)g,
        (__attribute__((address_space(3))) unsigned int*)l, 16, 0, 0);
}

// ---------- kernel 1: transpose [b][256][4096] f32 -> [b][4096][256] bf16 ----------
__global__ __launch_bounds__(256) void transpose_cvt(
    const float* __restrict__ in, ushort_t* __restrict__ outp,
    size_t in_bstride, size_t out_bstride)
{
    __shared__ float tile[64][65];
    const int tid = threadIdx.x;
    const int n0 = blockIdx.x * 64, d0 = blockIdx.y * 64, b = blockIdx.z;
    const float* ib = in + (size_t)b * in_bstride;
    ushort_t* ob = outp + (size_t)b * out_bstride;
    const int nl = tid & 63, dg = tid >> 6;
#pragma unroll
    for (int i = 0; i < 16; i++) {
        int dl = dg + i * 4;
        tile[dl][nl] = ib[(size_t)(d0 + dl) * NQ + n0 + nl];
    }
    __syncthreads();
    const int dl = tid & 63, ng = tid >> 6;
#pragma unroll
    for (int i = 0; i < 16; i++) {
        int nn = ng + i * 4;
        ob[(size_t)(n0 + nn) * ND + d0 + dl] = f2bf(tile[dl][nn]);
    }
}

// ---------- kernel 2: avg-pool 2x2 in [m][d] bf16 layout ----------
__global__ void pool_kernel(ushort_t* __restrict__ Ball, int Wlo, int in_off, int out_off)
{
    int t = blockIdx.x * 256 + threadIdx.x;
    int d = t & 255;
    int rest = t >> 8;
    int Nl = Wlo * Wlo;
    int m = rest % Nl;
    int b = rest / Nl;
    if (b >= NB) return;
    int y = m / Wlo, x = m - y * Wlo;
    int Wi = Wlo * 2;
    const ushort_t* src = Ball + (size_t)b * MPAD * ND;
    float s = 0.f;
#pragma unroll
    for (int iy = 0; iy < 2; iy++)
#pragma unroll
        for (int ix = 0; ix < 2; ix++)
            s += bf2f(src[(size_t)(in_off + (2 * y + iy) * Wi + (2 * x + ix)) * ND + d]);
    Ball[(size_t)b * MPAD * ND + (size_t)(out_off + m) * ND + d] = f2bf(s * 0.25f);
}

// ---------- kernel 2b: per-(batch,level,query) integer window base table ----------
__global__ void make_tbl(const float* __restrict__ coords, int* __restrict__ tbl)
{
    int t = blockIdx.x * 256 + threadIdx.x;     // b*4096 + q
    int b = t >> 12, q = t & 4095;
    float cx = coords[((size_t)b * 2 + 0) * NQ + q];
    float cy = coords[((size_t)b * 2 + 1) * NQ + q];
#pragma unroll
    for (int lvl = 0; lvl < 4; lvl++) {
        float s = 1.0f / (float)(1 << lvl);
        int x0 = (int)floorf(cx * s);
        int y0 = (int)floorf(cy * s);
        tbl[((b * 4 + lvl) << 12) + q] = (x0 & 0xffff) | (y0 << 16);
    }
}

// ---------- kernel 3: dbuf bf16 MFMA GEMM with compacted window epilogue ----------
// grid.x = 5504 = 4 batches * 32 n-tiles * 43 m-tiles, XCD-swizzled
__global__ __launch_bounds__(256) void gemm_corr(
    const ushort_t* __restrict__ A,     // [NB][4096][256] bf16
    const ushort_t* __restrict__ Bm,    // [NB][MPAD][256] bf16
    ushort_t* __restrict__ compact,     // [NB][4096][400] bf16
    const int* __restrict__ tbl)        // [NB][4][4096] packed (x0,y0)
{
    __shared__ ushort_t As[2][128 * 32];
    __shared__ ushort_t Bs[2][128 * 32];

    // bijective XCD-chunk swizzle: 5504 = 8 * 688
    const int l   = blockIdx.x;
    const int wg  = (l & 7) * 688 + (l >> 3);
    const int z   = wg / 1376;
    const int rem = wg - z * 1376;
    const int by  = rem / 43;
    const int bxt = rem - by * 43;

    int lvl, lbase, mbase;
    if (bxt < 32)      { lvl = 0; lbase = bxt * 128;        mbase = lbase; }
    else if (bxt < 40) { lvl = 1; lbase = (bxt - 32) * 128; mbase = 4096 + lbase; }
    else if (bxt < 42) { lvl = 2; lbase = (bxt - 40) * 128; mbase = 5120 + lbase; }
    else               { lvl = 3; lbase = 0;                mbase = 5376; }

    const int tid  = threadIdx.x;
    const int lane = tid & 63;
    const int wv   = tid >> 6;
    const int wr   = wv >> 1, wc = wv & 1;

    const ushort_t* Ab = A  + ((size_t)z * NQ   + (size_t)by * 128) * ND;
    const ushort_t* Bb = Bm + ((size_t)z * MPAD + (size_t)mbase) * ND;

    f4 acc[4][4] = {};
    const int r0 = tid >> 2;
    const int c8 = tid & 3;

#define STAGE(buf, kk)                                                              \
    gload_lds16(Ab + (size_t)r0 * ND + (kk) + c8 * 8,        &As[buf][tid * 8]);     \
    gload_lds16(Ab + (size_t)(64 + r0) * ND + (kk) + c8 * 8, &As[buf][(256+tid)*8]); \
    gload_lds16(Bb + (size_t)r0 * ND + (kk) + c8 * 8,        &Bs[buf][tid * 8]);     \
    gload_lds16(Bb + (size_t)(64 + r0) * ND + (kk) + c8 * 8, &Bs[buf][(256+tid)*8]);

    STAGE(0, 0);
#pragma unroll
    for (int t = 0; t < 8; ++t) {
        const int cur = t & 1;
        if (t < 7) {
            STAGE(cur ^ 1, (t + 1) * 32);
            asm volatile("s_waitcnt vmcnt(4)" ::: "memory");
        } else {
            asm volatile("s_waitcnt vmcnt(0)" ::: "memory");
        }
        __builtin_amdgcn_s_barrier();       // buf[cur] fully staged by all waves
        asm volatile("" ::: "memory");

        bfrag a[4], bb[4];
#pragma unroll
        for (int mi = 0; mi < 4; mi++)
            a[mi] = *reinterpret_cast<const bfrag*>(
                &As[cur][(wr * 64 + mi * 16 + (lane & 15)) * 32 + (lane >> 4) * 8]);
#pragma unroll
        for (int ni = 0; ni < 4; ni++)
            bb[ni] = *reinterpret_cast<const bfrag*>(
                &Bs[cur][(wc * 64 + ni * 16 + (lane & 15)) * 32 + (lane >> 4) * 8]);
#pragma unroll
        for (int mi = 0; mi < 4; mi++)
#pragma unroll
            for (int ni = 0; ni < 4; ni++)
                acc[mi][ni] = __builtin_amdgcn_mfma_f32_16x16x32_bf16(
                    a[mi], bb[ni], acc[mi][ni], 0, 0, 0);

        __builtin_amdgcn_s_barrier();       // all waves done reading buf[cur]
        asm volatile("" ::: "memory");
    }
#undef STAGE

    // ---- compacted epilogue: keep only dots inside some query's 10x10 window ----
    const int row_base    = by * 128 + wr * 64 + ((lane >> 4) << 2);
    const int col_in_lvl0 = lbase + wc * 64 + (lane & 15);
    const unsigned Wm1  = (64u >> lvl) - 1u;
    const int logW      = 6 - lvl;
    const int* tb       = tbl + (((size_t)z * 4 + lvl) << 12);
    ushort_t* cmp       = compact + (size_t)z * NQ * 400 + lvl * 100;

#pragma unroll
    for (int mi = 0; mi < 4; mi++)
#pragma unroll
        for (int j = 0; j < 4; j++) {
            int q  = row_base + mi * 16 + j;
            int xy = tb[q];
            int x0 = xy & 0xffff, y0 = xy >> 16;
#pragma unroll
            for (int ni = 0; ni < 4; ni++) {
                int cl = col_in_lvl0 + ni * 16;
                unsigned u = (unsigned)((int)(cl & Wm1) - x0 + 4);
                unsigned v = (unsigned)((cl >> logW) - y0 + 4);
                if (u < 10u && v < 10u)
                    cmp[(size_t)q * 400 + v * 10 + u] =
                        f2bf(acc[mi][ni][j] * 0.0625f);
            }
        }
}

// ---------- kernel 4: bilinear sampling from the compact window buffer ----------
__global__ __launch_bounds__(256) void sample_kernel(
    const ushort_t* __restrict__ compact,  // [NB][4096][400] bf16
    const float* __restrict__ coords,
    float* __restrict__ out)               // [NB][324][64][64] f32
{
    __shared__ int   X0s[16], Y0s[16];
    __shared__ float wxs[16], wys[16];
    __shared__ float Dl[16 * 101];
    const int tid = threadIdx.x;
    const int g   = blockIdx.x;
    const int lvl = blockIdx.y;
    const int b   = blockIdx.z;
    const int Wl  = NW >> lvl;

    if (tid < 16) {
        int q = g * 16 + tid;
        float cx = coords[(size_t)(b * 2 + 0) * NQ + q];
        float cy = coords[(size_t)(b * 2 + 1) * NQ + q];
        float s = 1.0f / (float)(1 << lvl);
        float xl = cx * s, yl = cy * s;
        float fx = floorf(xl), fy = floorf(yl);
        X0s[tid] = (int)fx;
        Y0s[tid] = (int)fy;
        wxs[tid] = xl - fx;
        wys[tid] = yl - fy;
    }
    __syncthreads();

#pragma unroll
    for (int r = 0; r < 7; r++) {
        int e = r * 256 + tid;
        if (e < 16 * 100) {
            int qi = e / 100;
            int el = e - qi * 100;
            int v = el / 10;
            int u = el - v * 10;
            int xx = X0s[qi] - 4 + u;
            int yy = Y0s[qi] - 4 + v;
            float val = 0.f;
            if ((unsigned)xx < (unsigned)Wl && (unsigned)yy < (unsigned)Wl)
                val = bf2f(compact[((size_t)b * NQ + g * 16 + qi) * 400
                                   + lvl * 100 + el]);
            Dl[qi * 101 + el] = val;
        }
    }
    __syncthreads();

#pragma unroll
    for (int r = 0; r < 6; r++) {
        int e = r * 256 + tid;
        if (e < 16 * 81) {
            int qi = e & 15;
            int c = e >> 4;
            int i = c / 9;            // x-offset grid index
            int j = c - i * 9;        // y-offset grid index
            float wx = wxs[qi], wy = wys[qi];
            const float* dq = &Dl[qi * 101];
            float d00 = dq[j * 10 + i];
            float d10 = dq[j * 10 + i + 1];
            float d01 = dq[(j + 1) * 10 + i];
            float d11 = dq[(j + 1) * 10 + i + 1];
            float vx0 = d00 + wx * (d10 - d00);
            float vx1 = d01 + wx * (d11 - d01);
            float val = vx0 + wy * (vx1 - vx0);
            out[((size_t)b * NCH + lvl * 81 + c) * NQ + g * 16 + qi] = val;
        }
    }
}

extern "C" void kernel_launch(void* const* d_in, const int* in_sizes, int n_in,
                              void* d_out, int out_size, void* d_ws, size_t ws_size,
                              hipStream_t stream)
{
    const float* fmap1  = (const float*)d_in[0];
    const float* fmap2  = (const float*)d_in[1];
    const float* coords = (const float*)d_in[2];
    float* out = (float*)d_out;

    char* ws = (char*)d_ws;
    const size_t A_BYTES   = (size_t)NB * NQ * ND * 2;     //  8.4 MB
    const size_t B_BYTES   = (size_t)NB * MPAD * ND * 2;   // 11.3 MB
    const size_t CMP_BYTES = (size_t)NB * NQ * 400 * 2;    // 13.1 MB
    ushort_t* Abf  = (ushort_t*)ws;
    ushort_t* Ball = (ushort_t*)(ws + A_BYTES);
    ushort_t* cmp  = (ushort_t*)(ws + A_BYTES + B_BYTES);
    int*      tbl  = (int*)(ws + A_BYTES + B_BYTES + CMP_BYTES);

    transpose_cvt<<<dim3(64, 4, NB), 256, 0, stream>>>(fmap1, Abf,  (size_t)ND * NQ, (size_t)NQ * ND);
    transpose_cvt<<<dim3(64, 4, NB), 256, 0, stream>>>(fmap2, Ball, (size_t)ND * NQ, (size_t)MPAD * ND);

    pool_kernel<<<(NB * 1024 * ND) / 256, 256, 0, stream>>>(Ball, 32, 0,    4096);
    pool_kernel<<<(NB * 256  * ND) / 256, 256, 0, stream>>>(Ball, 16, 4096, 5120);
    pool_kernel<<<(NB * 64   * ND) / 256, 256, 0, stream>>>(Ball, 8,  5120, 5376);

    make_tbl<<<(NB * NQ) / 256, 256, 0, stream>>>(coords, tbl);

    gemm_corr<<<dim3(43 * 32 * NB), 256, 0, stream>>>(Abf, Ball, cmp, tbl);

    sample_kernel<<<dim3(256, NLVL, NB), 256, 0, stream>>>(cmp, coords, out);
}